// Round 3
// baseline (93.791 us; speedup 1.0000x reference)
//
#include <hip/hip_runtime.h>

// AdderNet forward: out[n,h,w,f] = sum_{dh,dw,c} |Xpad[n,h+dh,w+dw,c] - F[f,dh,dw,c]|
// N=8, H=W=32, C=32, c_out=64, k=3, pad=1. fp32.
//
// R3: CALIBRATION ROUND. Kernel body identical to R2 (verified, absmax 2.0
// vs 7.88 threshold). kernel_launch fires it 3x back-to-back (idempotent:
// same inputs -> same output each time) so kernel time can be extracted from
// total dur: k = (dur_R3 - dur_R2)/2. This disambiguates "kernel ~5us,
// harness-floor-bound" from "kernel ~25us, filter loads still VMEM-bound".

#define BLOCK 256

__global__ __launch_bounds__(256, 2) void adder_fwd(const float* __restrict__ X,
                                                    const float* __restrict__ Fg,
                                                    float* __restrict__ out) {
    __shared__ float Xs[4 * 34 * 36];   // [row 0..3][wpos 0..33][c 0..31], wpos stride 36

    const int b = blockIdx.x;
    const int fq = b & 3;            // filter quarter (16 filters)
    const int hp = (b >> 2) & 15;    // h pair
    const int n = b >> 6;
    const int h0 = hp * 2;
    const int tid = threadIdx.x;

    // ---- stage X tile: rows h0-1..h0+2, w -1..32, zero padded. 4*34*8 = 1088 float4
    #pragma unroll
    for (int i = 0; i < 5; ++i) {
        int idx = tid + BLOCK * i;          // float4 slot
        if (idx < 1088) {
            int c4 = idx & 7;
            int t  = idx >> 3;              // 0..135 = rr*34 + wc
            int wc = t % 34;
            int rr = t / 34;                // 0..3
            int hr = h0 + rr - 1;
            int gw = wc - 1;
            float4 v = make_float4(0.f, 0.f, 0.f, 0.f);
            if ((unsigned)hr < 32u && (unsigned)gw < 32u) {
                v = ((const float4*)(X + (((size_t)n * 32 + hr) * 32 + gw) * 32))[c4];
            }
            ((float4*)(Xs + (rr * 34 + wc) * 36))[c4] = v;
        }
    }
    __syncthreads();

    const int w    = tid & 31;
    const int hh   = (tid >> 5) & 1;
    const int wave = __builtin_amdgcn_readfirstlane(tid >> 6);
    const int f0   = fq * 16 + wave * 4;

    const float* fb = Fg + (size_t)f0 * 288;   // 4 filters x 288, wave-uniform base

    float a0 = 0.f, a1 = 0.f, a2 = 0.f, a3 = 0.f;

    #pragma unroll
    for (int r = 0; r < 3; ++r) {
        #pragma unroll
        for (int dw = 0; dw < 3; ++dw) {
            const float4* xp = (const float4*)(Xs + ((hh + r) * 34 + (w + dw)) * 36);
            const float*  ftap = fb + (r * 3 + dw) * 32;
            #pragma unroll
            for (int c4 = 0; c4 < 8; ++c4) {
                float4 xv = xp[c4];
                float4 f0v = ((const float4*)(ftap + 0 * 288))[c4];
                float4 f1v = ((const float4*)(ftap + 1 * 288))[c4];
                float4 f2v = ((const float4*)(ftap + 2 * 288))[c4];
                float4 f3v = ((const float4*)(ftap + 3 * 288))[c4];
                a0 += fabsf(xv.x - f0v.x) + fabsf(xv.y - f0v.y)
                    + fabsf(xv.z - f0v.z) + fabsf(xv.w - f0v.w);
                a1 += fabsf(xv.x - f1v.x) + fabsf(xv.y - f1v.y)
                    + fabsf(xv.z - f1v.z) + fabsf(xv.w - f1v.w);
                a2 += fabsf(xv.x - f2v.x) + fabsf(xv.y - f2v.y)
                    + fabsf(xv.z - f2v.z) + fabsf(xv.w - f2v.w);
                a3 += fabsf(xv.x - f3v.x) + fabsf(xv.y - f3v.y)
                    + fabsf(xv.z - f3v.z) + fabsf(xv.w - f3v.w);
            }
        }
    }

    float4* o4 = (float4*)out;
    o4[(((size_t)n * 32 + h0 + hh) * 32 + w) * 16 + (f0 >> 2)] =
        make_float4(a0, a1, a2, a3);
}

extern "C" void kernel_launch(void* const* d_in, const int* in_sizes, int n_in,
                              void* d_out, int out_size, void* d_ws, size_t ws_size,
                              hipStream_t stream) {
    const float* X = (const float*)d_in[0];
    const float* F = (const float*)d_in[1];
    float* out = (float*)d_out;
    // 3x identical launches: calibration (see header comment). Idempotent.
    adder_fwd<<<dim3(512), dim3(256), 0, stream>>>(X, F, out);
    adder_fwd<<<dim3(512), dim3(256), 0, stream>>>(X, F, out);
    adder_fwd<<<dim3(512), dim3(256), 0, stream>>>(X, F, out);
}

// Round 4
// 74.893 us; speedup vs baseline: 1.2523x; 1.2523x over previous
//
#include <hip/hip_runtime.h>

// AdderNet forward: out[n,h,w,f] = sum_{dh,dw,c} |Xpad[n,h+dh,w+dw,c] - F[f,dh,dw,c]|
// N=8, H=W=32, C=32, c_out=64, k=3, pad=1. fp32.
//
// R4: un-mix the wait counters. R2 put filters on the scalar path (s_load,
// lgkmcnt) while x came from LDS (ds_read, also lgkmcnt); scalar loads return
// out-of-order vs LDS so the compiler serializes with conservative waits
// (~8us excess, calibrated R3). Now filters are per-lane VECTOR loads with a
// wave-uniform address (no readfirstlane -> stays VMEM): HW broadcast, one
// 64B line per access, 4.6KB/block filter set is L1-resident. Filter waits
// move to vmcnt; x ds_reads own lgkmcnt exclusively; both overlap under VALU.
// Grid 512 = (n:8, hpair:16, fq:4). Block 256 = 4 waves; wave = (hh:2, w:32),
// 4 filters per wave. X tile in LDS, wpos stride 36 (balanced: 8 words/bank).

#define BLOCK 256

__global__ __launch_bounds__(256, 2) void adder_fwd(const float* __restrict__ X,
                                                    const float* __restrict__ Fg,
                                                    float* __restrict__ out) {
    __shared__ float Xs[4 * 34 * 36];   // [row 0..3][wpos 0..33][c 0..31], wpos stride 36

    const int b = blockIdx.x;
    const int fq = b & 3;            // filter quarter (16 filters)
    const int hp = (b >> 2) & 15;    // h pair
    const int n = b >> 6;
    const int h0 = hp * 2;
    const int tid = threadIdx.x;

    // ---- stage X tile: rows h0-1..h0+2, w -1..32, zero padded. 4*34*8 = 1088 float4
    #pragma unroll
    for (int i = 0; i < 5; ++i) {
        int idx = tid + BLOCK * i;          // float4 slot
        if (idx < 1088) {
            int c4 = idx & 7;
            int t  = idx >> 3;              // 0..135 = rr*34 + wc
            int wc = t % 34;
            int rr = t / 34;                // 0..3
            int hr = h0 + rr - 1;
            int gw = wc - 1;
            float4 v = make_float4(0.f, 0.f, 0.f, 0.f);
            if ((unsigned)hr < 32u && (unsigned)gw < 32u) {
                v = ((const float4*)(X + (((size_t)n * 32 + hr) * 32 + gw) * 32))[c4];
            }
            ((float4*)(Xs + (rr * 34 + wc) * 36))[c4] = v;
        }
    }
    __syncthreads();

    const int w    = tid & 31;
    const int hh   = (tid >> 5) & 1;
    // NOTE: no readfirstlane — keep this "divergent" to the compiler so the
    // filter loads stay on the VMEM path (vmcnt), not s_load (lgkmcnt).
    const int wave = tid >> 6;
    const int f0   = fq * 16 + wave * 4;

    const float* fb = Fg + (size_t)f0 * 288;   // 4 filters x 288; same addr all lanes

    float a0 = 0.f, a1 = 0.f, a2 = 0.f, a3 = 0.f;

    #pragma unroll
    for (int r = 0; r < 3; ++r) {
        #pragma unroll
        for (int dw = 0; dw < 3; ++dw) {
            const float4* xp = (const float4*)(Xs + ((hh + r) * 34 + (w + dw)) * 36);
            const float*  ftap = fb + (r * 3 + dw) * 32;
            #pragma unroll
            for (int c4 = 0; c4 < 8; ++c4) {
                float4 xv = xp[c4];
                float4 f0v = ((const float4*)(ftap + 0 * 288))[c4];
                float4 f1v = ((const float4*)(ftap + 1 * 288))[c4];
                float4 f2v = ((const float4*)(ftap + 2 * 288))[c4];
                float4 f3v = ((const float4*)(ftap + 3 * 288))[c4];
                a0 += fabsf(xv.x - f0v.x) + fabsf(xv.y - f0v.y)
                    + fabsf(xv.z - f0v.z) + fabsf(xv.w - f0v.w);
                a1 += fabsf(xv.x - f1v.x) + fabsf(xv.y - f1v.y)
                    + fabsf(xv.z - f1v.z) + fabsf(xv.w - f1v.w);
                a2 += fabsf(xv.x - f2v.x) + fabsf(xv.y - f2v.y)
                    + fabsf(xv.z - f2v.z) + fabsf(xv.w - f2v.w);
                a3 += fabsf(xv.x - f3v.x) + fabsf(xv.y - f3v.y)
                    + fabsf(xv.z - f3v.z) + fabsf(xv.w - f3v.w);
            }
        }
    }

    // out[((n*32 + h0+hh)*32 + w)*64 + f0 .. f0+3] as one float4
    float4* o4 = (float4*)out;
    o4[(((size_t)n * 32 + h0 + hh) * 32 + w) * 16 + (f0 >> 2)] =
        make_float4(a0, a1, a2, a3);
}

extern "C" void kernel_launch(void* const* d_in, const int* in_sizes, int n_in,
                              void* d_out, int out_size, void* d_ws, size_t ws_size,
                              hipStream_t stream) {
    const float* X = (const float*)d_in[0];
    const float* F = (const float*)d_in[1];
    float* out = (float*)d_out;
    adder_fwd<<<dim3(512), dim3(256), 0, stream>>>(X, F, out);
}

// Round 5
// 69.892 us; speedup vs baseline: 1.3419x; 1.0716x over previous
//
#include <hip/hip_runtime.h>

// AdderNet forward: out[n,h,w,f] = sum_{dh,dw,c} |Xpad[n,h+dh,w+dw,c] - F[f,dh,dw,c]|
// N=8, H=W=32, C=32, c_out=64, k=3, pad=1. fp32.
//
// R5: register-persistent filters. Thread=(c4 wave 0..7, f lane 0..63);
// each lane holds its filter slice (9 taps x 4 ch = 36 VGPRs) for the whole
// block -> zero filter traffic in the K-loop (R2/R4 both died streaming
// 288 float4/wave of filter data through SGPRs/VMEM). x is wave-uniform
// (fixed c4 per wave) -> 10 s_load_dwordx4 per row from a PADDED X copy in
// d_ws (prep kernel; no edge branches so scalar loads are clean). Prep also
// transposes F -> Ft2[tap][c4][f][4] so the once-per-block Freg load is
// perfectly coalesced. c4-partials reduced via LDS (stride-9 pad: 2-way
// conflicts only = free), coalesced epilogue stores.
// Grid 1024 = (n:8, h:32, wb:4); block 512 = 8 waves. ~630 VALU/lane.

#define XPAD_F4 73984            // 8*34*34*8 float4s
#define FT2_F4  4608             // 9*8*64 float4s

__global__ void adder_prep(const float* __restrict__ X,
                           const float* __restrict__ Fg,
                           float4* __restrict__ ws) {
    int idx = blockIdx.x * 256 + threadIdx.x;
    if (idx < XPAD_F4) {
        // Xpad[n][hp 0..33][wp 0..33][c4] ; hp=h+1, wp=w+1, zero padding
        int c4 = idx & 7;
        int t  = idx >> 3;
        int wp = t % 34;
        int t2 = t / 34;
        int hp = t2 % 34;
        int n  = t2 / 34;
        int h = hp - 1, w = wp - 1;
        float4 v = make_float4(0.f, 0.f, 0.f, 0.f);
        if ((unsigned)h < 32u && (unsigned)w < 32u)
            v = ((const float4*)X)[((n * 32 + h) * 32 + w) * 8 + c4];
        ws[idx] = v;
    } else if (idx < XPAD_F4 + FT2_F4) {
        // Ft2[tap][c4][f] (float4) = F[f][tap][c4*4..+3]
        int j = idx - XPAD_F4;
        int f   = j & 63;
        int t3  = j >> 6;
        int c4  = t3 & 7;
        int tap = t3 >> 3;
        ws[idx] = ((const float4*)Fg)[f * 72 + tap * 8 + c4];
    }
}

__global__ __launch_bounds__(512, 4) void adder_main(const float* __restrict__ ws,
                                                     float* __restrict__ out) {
    __shared__ float part[8 * 64 * 9];   // [c4][f][w(pad 9)] : 18432 B

    const float*  Xpad = ws;                           // float idx
    const float4* Ft2  = (const float4*)(ws + XPAD_F4 * 4);

    const int b  = blockIdx.x;
    const int wb = b & 3;
    const int h  = (b >> 2) & 31;
    const int n  = b >> 7;
    const int w0 = wb * 8;

    const int tid = threadIdx.x;
    const int f   = tid & 63;
    const int c4  = __builtin_amdgcn_readfirstlane(tid >> 6);  // wave-uniform 0..7

    // Persistent filter slice: 9 taps x 4 channels = 36 VGPRs. Coalesced load.
    float4 Freg[9];
    #pragma unroll
    for (int t = 0; t < 9; ++t)
        Freg[t] = Ft2[(t * 8 + c4) * 64 + f];

    float acc[8];
    #pragma unroll
    for (int w = 0; w < 8; ++w) acc[w] = 0.f;

    #pragma unroll
    for (int dh = 0; dh < 3; ++dh) {
        // padded row hp = h+dh, chunks wp = w0 .. w0+9, channels c4*4..+3
        const float4* xr =
            (const float4*)(Xpad + (((n * 34 + h + dh) * 34 + w0) * 32 + c4 * 4));
        float4 xrow[10];
        #pragma unroll
        for (int k = 0; k < 10; ++k) xrow[k] = xr[k * 8];   // uniform addr -> s_load

        #pragma unroll
        for (int w = 0; w < 8; ++w) {
            #pragma unroll
            for (int dw = 0; dw < 3; ++dw) {
                float4 xv = xrow[w + dw];
                float4 fv = Freg[dh * 3 + dw];
                acc[w] += fabsf(xv.x - fv.x) + fabsf(xv.y - fv.y)
                        + fabsf(xv.z - fv.z) + fabsf(xv.w - fv.w);
            }
        }
    }

    // cross-wave (c4) reduction through LDS; stride 9 -> banks spread (2-way)
    #pragma unroll
    for (int w = 0; w < 8; ++w)
        part[(c4 * 64 + f) * 9 + w] = acc[w];
    __syncthreads();

    const int wp = tid >> 6;     // 0..7
    const int fp = tid & 63;
    float s = 0.f;
    #pragma unroll
    for (int cc = 0; cc < 8; ++cc)
        s += part[(cc * 64 + fp) * 9 + wp];

    out[(((size_t)n * 32 + h) * 32 + (w0 + wp)) * 64 + fp] = s;
}

extern "C" void kernel_launch(void* const* d_in, const int* in_sizes, int n_in,
                              void* d_out, int out_size, void* d_ws, size_t ws_size,
                              hipStream_t stream) {
    const float* X = (const float*)d_in[0];
    const float* F = (const float*)d_in[1];
    float* out = (float*)d_out;
    float4* ws4 = (float4*)d_ws;

    adder_prep<<<dim3((XPAD_F4 + FT2_F4 + 255) / 256), dim3(256), 0, stream>>>(X, F, ws4);
    adder_main<<<dim3(1024), dim3(512), 0, stream>>>((const float*)d_ws, out);
}